// Round 3
// baseline (4223.906 us; speedup 1.0000x reference)
//
#include <hip/hip_runtime.h>
#include <math.h>

typedef _Float16 h2_t __attribute__((ext_vector_type(2)));
typedef _Float16 h8_t __attribute__((ext_vector_type(8)));
typedef float    f4_t __attribute__((ext_vector_type(4)));

#define T_ 512
#define B_ 64
#define E_ 256
#define H_ 256
#define G_ 1024   // 4*H
#define K_ 16
#define NEG_ (-10000.0f)
#define START_ 14
#define STOP_ 15

#if defined(__has_builtin)
#if __has_builtin(__builtin_amdgcn_fdot2)
#define HAVE_FDOT2 1
#endif
#endif

static __device__ __forceinline__ float dot2(h2_t a, h2_t b, float c) {
#ifdef HAVE_FDOT2
    return __builtin_amdgcn_fdot2(a, b, c, false);
#else
    return fmaf((float)a[0], (float)b[0], fmaf((float)a[1], (float)b[1], c));
#endif
}

// ---------------------------------------------------------------------------
// Prep: pack w_hh rows k=200..255 as fp16, layout [dir][p=0..6][row 0..1023]
// (16B per entry, lane-consecutive in row for coalesced per-step refetch).
// ---------------------------------------------------------------------------
__global__ __launch_bounds__(256)
void prep_weights(const float* __restrict__ w_hh_f,
                  const float* __restrict__ w_hh_b,
                  _Float16* __restrict__ wpack)
{
    int id = blockIdx.x * 256 + threadIdx.x;   // h8 index, 14336 total
    if (id < 14336) {
        int d = id / 7168, r2 = id % 7168;
        int p = r2 >> 10, r = r2 & 1023;
        const float* src = (d ? w_hh_b : w_hh_f) + r * 256 + 200 + p * 8;
        h8_t o;
        #pragma unroll
        for (int i = 0; i < 8; ++i) o[i] = (_Float16)src[i];
        ((h8_t*)wpack)[id] = o;
    }
}

// ---------------------------------------------------------------------------
// Kernel A: input-gate GEMM via f16 MFMA 16x16x32.
// Block = (t, dir): 64 M-rows (all b), N=1024 in 4 passes of 256.
// A staged once to LDS (fp32->fp16), B staged per 32-k-chunk (fp32->fp16).
// Bias NOT added (recurrence adds it).
// ---------------------------------------------------------------------------
__global__ __launch_bounds__(256)
void gates_mfma(const int* __restrict__ sentence,
                const float* __restrict__ emb,
                const float* __restrict__ w_ih_f,
                const float* __restrict__ w_ih_b,
                _Float16* __restrict__ gin_f,
                _Float16* __restrict__ gin_b)
{
    __shared__ _Float16 As[64 * 264];     // 64 rows x 256 (+8 pad)
    __shared__ _Float16 Bs[256 * 40];     // 256 rows x 32 (+8 pad)
    __shared__ int sidx[64];

    const int bm  = blockIdx.x;           // t
    const int dir = blockIdx.y;
    const int tid = threadIdx.x;

    const float* __restrict__ wih = dir ? w_ih_b : w_ih_f;
    _Float16* __restrict__ gout   = dir ? gin_b : gin_f;

    if (tid < 64) sidx[tid] = sentence[tid * T_ + bm];
    __syncthreads();

    // stage A: thread (r = tid&63, kq = tid>>6) covers 64 floats
    {
        const int r = tid & 63, kq = tid >> 6;
        const float4* src = (const float4*)(emb + (size_t)sidx[r] * 256 + kq * 64);
        _Float16* dst = As + r * 264 + kq * 64;
        #pragma unroll
        for (int c = 0; c < 8; ++c) {
            float4 v0 = src[2 * c], v1 = src[2 * c + 1];
            h8_t o;
            o[0] = (_Float16)v0.x; o[1] = (_Float16)v0.y;
            o[2] = (_Float16)v0.z; o[3] = (_Float16)v0.w;
            o[4] = (_Float16)v1.x; o[5] = (_Float16)v1.y;
            o[6] = (_Float16)v1.z; o[7] = (_Float16)v1.w;
            *(h8_t*)(dst + c * 8) = o;
        }
    }

    const int wave = tid >> 6, lane = tid & 63;
    const int l15 = lane & 15, quad = lane >> 4;

    for (int pass = 0; pass < 4; ++pass) {
        const int n0 = pass * 256;
        f4_t acc[16];
        #pragma unroll
        for (int nt = 0; nt < 16; ++nt) acc[nt] = (f4_t){0.f, 0.f, 0.f, 0.f};

        for (int kc = 0; kc < 8; ++kc) {
            __syncthreads();   // previous Bs reads done (also covers A-stage on first iter)
            {
                const float4* bsrc = (const float4*)(wih + (size_t)(n0 + tid) * 256 + kc * 32);
                #pragma unroll
                for (int c = 0; c < 4; ++c) {
                    float4 v0 = bsrc[2 * c], v1 = bsrc[2 * c + 1];
                    h8_t o;
                    o[0] = (_Float16)v0.x; o[1] = (_Float16)v0.y;
                    o[2] = (_Float16)v0.z; o[3] = (_Float16)v0.w;
                    o[4] = (_Float16)v1.x; o[5] = (_Float16)v1.y;
                    o[6] = (_Float16)v1.z; o[7] = (_Float16)v1.w;
                    *(h8_t*)(Bs + tid * 40 + c * 8) = o;
                }
            }
            __syncthreads();
            h8_t a = *(const h8_t*)(As + (wave * 16 + l15) * 264 + kc * 32 + quad * 8);
            #pragma unroll
            for (int nt = 0; nt < 16; ++nt) {
                h8_t b = *(const h8_t*)(Bs + (nt * 16 + l15) * 40 + quad * 8);
                acc[nt] = __builtin_amdgcn_mfma_f32_16x16x32_f16(a, b, acc[nt], 0, 0, 0);
            }
        }

        const size_t mbase = (size_t)bm * 64 + wave * 16 + quad * 4;
        #pragma unroll
        for (int nt = 0; nt < 16; ++nt) {
            const int col = n0 + nt * 16 + l15;
            #pragma unroll
            for (int r = 0; r < 4; ++r)
                gout[(mbase + r) * 1024 + col] = (_Float16)acc[nt][r];
        }
    }
}

// ---------------------------------------------------------------------------
// Kernel B: persistent LSTM recurrence. 128 blocks = (dir, b), 512 threads,
// __launch_bounds__(512,2) -> 256 VGPR cap. Thread q owns rows {q, q+512}:
// k=0..199 resident as 200 half2 VGPRs; k=200..255 refetched per step from
// wpack (L2-resident, shared across 64 blocks/dir) in two 28-reg groups.
// ---------------------------------------------------------------------------
__global__ __launch_bounds__(512, 2)
void lstm_persist(const _Float16* __restrict__ gin_f,
                  const _Float16* __restrict__ gin_b,
                  const float* __restrict__ w_hh_f,
                  const float* __restrict__ w_hh_b,
                  const float* __restrict__ b_f,
                  const float* __restrict__ b_b,
                  const _Float16* __restrict__ wpack,
                  float* __restrict__ hf, float* __restrict__ hb)
{
    __shared__ h2_t  h2buf[128];     // 256 h values, fp16 packed
    __shared__ float gbuf[1024];

    const int blk = blockIdx.x;
    const int dir = blk >> 6;
    const int b   = blk & 63;
    const int q   = threadIdx.x;     // 0..511

    const _Float16* __restrict__ gin = dir ? gin_b : gin_f;
    const float*    __restrict__ whh = dir ? w_hh_b : w_hh_f;
    const float*    __restrict__ bs  = dir ? b_b : b_f;
    float*          __restrict__ hout = dir ? hb : hf;

    // resident weights: rows q and q+512, k = 0..199 (100 half2 each)
    h2_t w0[100], w1[100];
    {
        const float2* r0 = (const float2*)(whh + (size_t)q * 256);
        const float2* r1 = (const float2*)(whh + (size_t)(q + 512) * 256);
        #pragma unroll
        for (int k = 0; k < 100; ++k) {
            float2 a = r0[k], c2 = r1[k];
            h2_t pa, pb;
            pa[0] = (_Float16)a.x;  pa[1] = (_Float16)a.y;
            pb[0] = (_Float16)c2.x; pb[1] = (_Float16)c2.y;
            w0[k] = pa; w1[k] = pb;
        }
    }
    const float bias0 = bs[q];
    const float bias1 = bs[q + 512];

    const h8_t* wp0 = (const h8_t*)wpack + (size_t)dir * 7168 + q;  // + p*1024
    const h8_t* wp1 = wp0 + 512;

    if (q < 128) { h2_t z; z[0] = (_Float16)0.f; z[1] = (_Float16)0.f; h2buf[q] = z; }
    float c = 0.f;
    __syncthreads();

    const long tstr = 64 * 1024;
    const long hstr = 64 * 256;
    const _Float16* gp = gin + (size_t)(dir ? 511 : 0) * tstr + (size_t)b * 1024 + q;
    float*          hp = hout + (size_t)(dir ? 511 : 0) * hstr + (size_t)b * 256 + q;
    const long gstep = dir ? -tstr : tstr;
    const long hstep = dir ? -hstr : hstr;

    union U4 { float4 f; h2_t h[4]; };

    for (int s = 0; s < T_; ++s) {
        float a0 = bias0 + (float)gp[0];
        float a1 = bias1 + (float)gp[512];

        // group 1: overflow packs for row q (28 VGPRs in flight)
        h8_t ov0[7];
        #pragma unroll
        for (int p = 0; p < 7; ++p) ov0[p] = wp0[(size_t)p * 1024];

        #pragma unroll
        for (int k4 = 0; k4 < 12; ++k4) {
            U4 u; u.f = ((const float4*)h2buf)[k4];
            a0 = dot2(w0[4*k4+0], u.h[0], a0); a1 = dot2(w1[4*k4+0], u.h[0], a1);
            a0 = dot2(w0[4*k4+1], u.h[1], a0); a1 = dot2(w1[4*k4+1], u.h[1], a1);
            a0 = dot2(w0[4*k4+2], u.h[2], a0); a1 = dot2(w1[4*k4+2], u.h[2], a1);
            a0 = dot2(w0[4*k4+3], u.h[3], a0); a1 = dot2(w1[4*k4+3], u.h[3], a1);
        }
        // consume group 1 (k = 200..255 of row q)
        #pragma unroll
        for (int p = 0; p < 7; ++p) {
            U4 u; u.f = ((const float4*)h2buf)[25 + p];
            const h2_t* o = (const h2_t*)&ov0[p];
            a0 = dot2(o[0], u.h[0], a0);
            a0 = dot2(o[1], u.h[1], a0);
            a0 = dot2(o[2], u.h[2], a0);
            a0 = dot2(o[3], u.h[3], a0);
        }
        // group 2: overflow packs for row q+512
        h8_t ov1[7];
        #pragma unroll
        for (int p = 0; p < 7; ++p) ov1[p] = wp1[(size_t)p * 1024];

        #pragma unroll
        for (int k4 = 12; k4 < 25; ++k4) {
            U4 u; u.f = ((const float4*)h2buf)[k4];
            a0 = dot2(w0[4*k4+0], u.h[0], a0); a1 = dot2(w1[4*k4+0], u.h[0], a1);
            a0 = dot2(w0[4*k4+1], u.h[1], a0); a1 = dot2(w1[4*k4+1], u.h[1], a1);
            a0 = dot2(w0[4*k4+2], u.h[2], a0); a1 = dot2(w1[4*k4+2], u.h[2], a1);
            a0 = dot2(w0[4*k4+3], u.h[3], a0); a1 = dot2(w1[4*k4+3], u.h[3], a1);
        }
        // consume group 2 (k = 200..255 of row q+512)
        #pragma unroll
        for (int p = 0; p < 7; ++p) {
            U4 u; u.f = ((const float4*)h2buf)[25 + p];
            const h2_t* o = (const h2_t*)&ov1[p];
            a1 = dot2(o[0], u.h[0], a1);
            a1 = dot2(o[1], u.h[1], a1);
            a1 = dot2(o[2], u.h[2], a1);
            a1 = dot2(o[3], u.h[3], a1);
        }

        gbuf[q] = a0;
        gbuf[q + 512] = a1;
        __syncthreads();
        if (q < 256) {
            float gi = gbuf[q], gf = gbuf[q + 256], gg = gbuf[q + 512], go = gbuf[q + 768];
            float si = 1.f / (1.f + expf(-gi));
            float sf = 1.f / (1.f + expf(-gf));
            float so = 1.f / (1.f + expf(-go));
            c = sf * c + si * tanhf(gg);
            float h = so * tanhf(c);
            hp[0] = h;
            ((_Float16*)h2buf)[q] = (_Float16)h;
        }
        gp += gstep;
        hp += hstep;
        __syncthreads();
    }
}

// ---------------------------------------------------------------------------
// Kernel C: feats[m, o] = concat(hf[m], hb[m]) . w_out[o, :] + b_out[o]
// ---------------------------------------------------------------------------
__global__ __launch_bounds__(256)
void feats_proj(const float* __restrict__ hf, const float* __restrict__ hb,
                const float* __restrict__ w_out, const float* __restrict__ b_out,
                float* __restrict__ feats)
{
    const int lane = threadIdx.x & 63;
    const int wv   = threadIdx.x >> 6;
    const int m    = blockIdx.x * 4 + wv;
    const int o    = lane & 15;
    const int q    = lane >> 4;

    const float* hsrc = (q < 2) ? (hf + (size_t)m * 256 + q * 128)
                                : (hb + (size_t)m * 256 + (q - 2) * 128);
    const float4* h4 = (const float4*)hsrc;
    const float4* w4 = (const float4*)(w_out + o * 512 + q * 128);

    float acc = 0.f;
    #pragma unroll
    for (int i = 0; i < 32; ++i) {
        float4 hv = h4[i], wvv = w4[i];
        acc = fmaf(hv.x, wvv.x, acc);
        acc = fmaf(hv.y, wvv.y, acc);
        acc = fmaf(hv.z, wvv.z, acc);
        acc = fmaf(hv.w, wvv.w, acc);
    }
    acc += __shfl_xor(acc, 16, 64);
    acc += __shfl_xor(acc, 32, 64);
    if (lane < 16) feats[(size_t)m * 16 + o] = acc + b_out[o];
}

// ---------------------------------------------------------------------------
// Kernel D: Viterbi + backtrace. One wave per batch element.
// ---------------------------------------------------------------------------
__global__ __launch_bounds__(64)
void viterbi(const float* __restrict__ feats, const float* __restrict__ trans,
             float* __restrict__ out)
{
    __shared__ unsigned char bp[T_][16];
    const int b    = blockIdx.x;
    const int lane = threadIdx.x;

    float tr[16];
    #pragma unroll
    for (int p = 0; p < 16; ++p)
        tr[p] = (lane < 16) ? trans[lane * 16 + p] : 0.f;

    float fv = (lane == START_) ? 0.f : NEG_;

    for (int t = 0; t < T_; ++t) {
        float best = -3.4e38f; int arg = 0;
        #pragma unroll
        for (int p = 0; p < 16; ++p) {
            float s = __shfl(fv, p, 64) + tr[p];
            if (s > best) { best = s; arg = p; }
        }
        float ft = (lane < 16) ? feats[((size_t)t * 64 + b) * 16 + lane] : 0.f;
        if (lane < 16) {
            fv = best + ft;
            bp[t][lane] = (unsigned char)arg;
        }
    }

    float term = fv + ((lane < 16) ? trans[STOP_ * 16 + lane] : 0.f);
    float v  = (lane < 16) ? term : -3.4e38f;
    int  idx = (lane < 16) ? lane : (1 << 20);
    #pragma unroll
    for (int off = 1; off < 64; off <<= 1) {
        float v2 = __shfl_xor(v, off, 64);
        int   i2 = __shfl_xor(idx, off, 64);
        if (v2 > v || (v2 == v && i2 < idx)) { v = v2; idx = i2; }
    }
    __syncthreads();
    if (lane == 0) {
        out[b] = v;
        int tag = idx;
        for (int t = T_ - 1; t >= 0; --t) {
            out[64 + (size_t)t * 64 + b] = (float)tag;
            tag = bp[t][tag];
        }
    }
}

// ---------------------------------------------------------------------------
extern "C" void kernel_launch(void* const* d_in, const int* in_sizes, int n_in,
                              void* d_out, int out_size, void* d_ws, size_t ws_size,
                              hipStream_t stream) {
    const int*   sentence = (const int*)d_in[0];
    const float* emb      = (const float*)d_in[1];
    const float* w_ih_f   = (const float*)d_in[2];
    const float* w_hh_f   = (const float*)d_in[3];
    const float* b_f      = (const float*)d_in[4];
    const float* w_ih_b   = (const float*)d_in[5];
    const float* w_hh_b   = (const float*)d_in[6];
    const float* b_b      = (const float*)d_in[7];
    const float* w_out    = (const float*)d_in[8];
    const float* b_out    = (const float*)d_in[9];
    const float* trans    = (const float*)d_in[10];
    float* out = (float*)d_out;

    // workspace: gin fp16 x2 | hf | hb | feats (fp32) | wpack fp16 (~203.6 MB)
    _Float16* gin_f = (_Float16*)d_ws;
    _Float16* gin_b = gin_f + (size_t)T_ * B_ * G_;
    float* hf    = (float*)(gin_b + (size_t)T_ * B_ * G_);
    float* hb    = hf + (size_t)T_ * B_ * H_;
    float* feats = hb + (size_t)T_ * B_ * H_;
    _Float16* wpack = (_Float16*)(feats + (size_t)T_ * B_ * K_);   // 14336 x h8

    prep_weights<<<56, 256, 0, stream>>>(w_hh_f, w_hh_b, wpack);
    gates_mfma<<<dim3(512, 2), 256, 0, stream>>>(sentence, emb, w_ih_f, w_ih_b,
                                                 gin_f, gin_b);
    lstm_persist<<<128, 512, 0, stream>>>(gin_f, gin_b, w_hh_f, w_hh_b,
                                          b_f, b_b, wpack, hf, hb);
    feats_proj<<<8192, 256, 0, stream>>>(hf, hb, w_out, b_out, feats);
    viterbi<<<64, 64, 0, stream>>>(feats, trans, out);
}

// Round 4
// 1650.898 us; speedup vs baseline: 2.5586x; 2.5586x over previous
//
#include <hip/hip_runtime.h>
#include <math.h>

typedef _Float16 h2_t  __attribute__((ext_vector_type(2)));
typedef _Float16 h8_t  __attribute__((ext_vector_type(8)));
typedef _Float16 h16_t __attribute__((ext_vector_type(16)));
typedef _Float16 h32_t __attribute__((ext_vector_type(32)));
typedef float    f4_t  __attribute__((ext_vector_type(4)));

#define T_ 512
#define B_ 64
#define E_ 256
#define H_ 256
#define G_ 1024   // 4*H
#define K_ 16
#define NEG_ (-10000.0f)
#define START_ 14
#define STOP_ 15

#if defined(__has_builtin)
#if __has_builtin(__builtin_amdgcn_fdot2)
#define HAVE_FDOT2 1
#endif
#endif

static __device__ __forceinline__ float dot2(h2_t a, h2_t b, float c) {
#ifdef HAVE_FDOT2
    return __builtin_amdgcn_fdot2(a, b, c, false);
#else
    return fmaf((float)a[0], (float)b[0], fmaf((float)a[1], (float)b[1], c));
#endif
}

// extract h2 pair P from a wider fp16 vector — template param keeps the
// shufflevector indices integer-constant (SSA, no alloca ever).
template <int P, typename V>
static __device__ __forceinline__ h2_t get2(V v) {
    return __builtin_shufflevector(v, v, 2 * P, 2 * P + 1);
}

// ---------------------------------------------------------------------------
// Prep: pack all weights to fp16 in the layouts the hot kernels want.
//  wreg : [dir][v=0..11][q=0..511] x 32 halves   (v<6: row q, k=v*32;
//         v>=6: row q+512, k=(v-6)*32)                         -> 768 KB
//  wlds : [dir][p=0..1][c=0..7][q=0..511] x 8 halves (row = c<4? q : q+512,
//         k = 192 + (c&3)*16 + p*8)                            -> 256 KB
//  wih16: [dir][row 0..1023][k 0..255] fp16 copy of w_ih       -> 1 MB
// ---------------------------------------------------------------------------
__global__ __launch_bounds__(256)
void prep_weights(const float* __restrict__ w_hh_f,
                  const float* __restrict__ w_hh_b,
                  const float* __restrict__ w_ih_f,
                  const float* __restrict__ w_ih_b,
                  _Float16* __restrict__ wreg,
                  _Float16* __restrict__ wlds,
                  _Float16* __restrict__ wih16)
{
    const int blk = blockIdx.x, tid = threadIdx.x;
    if (blk < 48) {                       // wreg: 12288 x h32
        int idx = blk * 256 + tid;
        int dir = idx / 6144, rem = idx % 6144;
        int v = rem / 512, q = rem % 512;
        int row = (v < 6) ? q : q + 512;
        int kb = (v % 6) * 32;
        const float* src = (dir ? w_hh_b : w_hh_f) + (size_t)row * 256 + kb;
        _Float16* dst = wreg + (size_t)idx * 32;
        #pragma unroll
        for (int i = 0; i < 32; ++i) dst[i] = (_Float16)src[i];
    } else if (blk < 112) {               // wlds: 16384 x h8
        int idx = (blk - 48) * 256 + tid;
        int dir = idx / 8192, rem = idx % 8192;
        int j = rem / 512, q = rem % 512;
        int p = j / 8, c = j % 8;
        int row = (c < 4) ? q : q + 512;
        int kb = 192 + (c & 3) * 16 + p * 8;
        const float* src = (dir ? w_hh_b : w_hh_f) + (size_t)row * 256 + kb;
        _Float16* dst = wlds + (size_t)idx * 8;
        #pragma unroll
        for (int i = 0; i < 8; ++i) dst[i] = (_Float16)src[i];
    } else {                              // wih16: 65536 x h8
        int idx = (blk - 112) * 256 + tid;
        int dir = idx / 32768, rem = idx % 32768;
        const float* src = (dir ? w_ih_b : w_ih_f) + (size_t)rem * 8;
        _Float16* dst = wih16 + (size_t)idx * 8;
        #pragma unroll
        for (int i = 0; i < 8; ++i) dst[i] = (_Float16)src[i];
    }
}

// ---------------------------------------------------------------------------
// Kernel A: input-gate GEMM via f16 MFMA 16x16x32.
// Block = (t, dir): 64 M-rows, N=1024 in 4 passes. B staged from
// pre-converted wih16 (pure h8 copies). Bias NOT added here.
// ---------------------------------------------------------------------------
__global__ __launch_bounds__(256)
void gates_mfma(const int* __restrict__ sentence,
                const float* __restrict__ emb,
                const _Float16* __restrict__ wih16,
                _Float16* __restrict__ gin_f,
                _Float16* __restrict__ gin_b)
{
    __shared__ _Float16 As[64 * 264];
    __shared__ _Float16 Bs[256 * 40];
    __shared__ int sidx[64];

    const int bm  = blockIdx.x;           // t
    const int dir = blockIdx.y;
    const int tid = threadIdx.x;

    const _Float16* __restrict__ wih = wih16 + (size_t)dir * 262144;
    _Float16* __restrict__ gout      = dir ? gin_b : gin_f;

    if (tid < 64) sidx[tid] = sentence[tid * T_ + bm];
    __syncthreads();

    {   // stage A (emb gather, fp32 -> fp16)
        const int r = tid & 63, kq = tid >> 6;
        const float4* src = (const float4*)(emb + (size_t)sidx[r] * 256 + kq * 64);
        _Float16* dst = As + r * 264 + kq * 64;
        #pragma unroll
        for (int c = 0; c < 8; ++c) {
            float4 v0 = src[2 * c], v1 = src[2 * c + 1];
            h8_t o;
            o[0] = (_Float16)v0.x; o[1] = (_Float16)v0.y;
            o[2] = (_Float16)v0.z; o[3] = (_Float16)v0.w;
            o[4] = (_Float16)v1.x; o[5] = (_Float16)v1.y;
            o[6] = (_Float16)v1.z; o[7] = (_Float16)v1.w;
            *(h8_t*)(dst + c * 8) = o;
        }
    }

    const int wave = tid >> 6, lane = tid & 63;
    const int l15 = lane & 15, quad = lane >> 4;

    for (int pass = 0; pass < 4; ++pass) {
        const int n0 = pass * 256;
        f4_t acc[16];
        #pragma unroll
        for (int nt = 0; nt < 16; ++nt) acc[nt] = (f4_t){0.f, 0.f, 0.f, 0.f};

        for (int kc = 0; kc < 8; ++kc) {
            __syncthreads();
            {
                const h8_t* bsrc = (const h8_t*)(wih + (size_t)(n0 + tid) * 256 + kc * 32);
                #pragma unroll
                for (int c = 0; c < 4; ++c)
                    *(h8_t*)(Bs + tid * 40 + c * 8) = bsrc[c];
            }
            __syncthreads();
            h8_t a = *(const h8_t*)(As + (wave * 16 + l15) * 264 + kc * 32 + quad * 8);
            #pragma unroll
            for (int nt = 0; nt < 16; ++nt) {
                h8_t b = *(const h8_t*)(Bs + (nt * 16 + l15) * 40 + quad * 8);
                acc[nt] = __builtin_amdgcn_mfma_f32_16x16x32_f16(a, b, acc[nt], 0, 0, 0);
            }
        }

        const size_t mbase = (size_t)bm * 64 + wave * 16 + quad * 4;
        #pragma unroll
        for (int nt = 0; nt < 16; ++nt) {
            const int col = n0 + nt * 16 + l15;
            #pragma unroll
            for (int r = 0; r < 4; ++r)
                gout[(mbase + r) * 1024 + col] = (_Float16)acc[nt][r];
        }
    }
}

// ---------------------------------------------------------------------------
// Kernel B: persistent LSTM. 128 blocks = (dir, b), 512 threads, 2 waves/EU.
// Thread q owns gate rows {q, q+512}. k in [0,192) lives in 12 h32 SSA
// vector VALUES (192 VGPRs, never an alloca); k in [192,256) lives in LDS
// (128 KB, conflict-free h8 layout). h broadcast via LDS, fp16 packed.
// ---------------------------------------------------------------------------
#define D4R(W, X, HV, P0) do {                                                \
    h2_t p0 = get2<0>(HV), p1 = get2<1>(HV), p2 = get2<2>(HV), p3 = get2<3>(HV); \
    a0 = dot2(get2<(P0)+0>(W), p0, a0); a1 = dot2(get2<(P0)+0>(X), p0, a1);   \
    a0 = dot2(get2<(P0)+1>(W), p1, a0); a1 = dot2(get2<(P0)+1>(X), p1, a1);   \
    a0 = dot2(get2<(P0)+2>(W), p2, a0); a1 = dot2(get2<(P0)+2>(X), p2, a1);   \
    a0 = dot2(get2<(P0)+3>(W), p3, a0); a1 = dot2(get2<(P0)+3>(X), p3, a1);   \
} while (0)

#define GRP(W, X, BB) do {                                                    \
    h8_t v0 = HB[(BB) + 0], v1 = HB[(BB) + 1], v2 = HB[(BB) + 2], v3 = HB[(BB) + 3]; \
    D4R(W, X, v0, 0); D4R(W, X, v1, 4); D4R(W, X, v2, 8); D4R(W, X, v3, 12);  \
} while (0)

#define DLDS(C) do {                                                          \
    h8_t wA0 = WS8[((C)) * 512 + q];                                          \
    h8_t wB0 = WS8[((C) + 4) * 512 + q];                                      \
    h8_t wA1 = WS8[(8 + (C)) * 512 + q];                                      \
    h8_t wB1 = WS8[(8 + (C) + 4) * 512 + q];                                  \
    h8_t u0 = HB[24 + 2 * (C)], u1 = HB[24 + 2 * (C) + 1];                    \
    D4R(wA0, wB0, u0, 0); D4R(wA1, wB1, u1, 0);                               \
} while (0)

__global__ __launch_bounds__(512, 2)
void lstm_persist(const _Float16* __restrict__ gin_f,
                  const _Float16* __restrict__ gin_b,
                  const _Float16* __restrict__ wreg,
                  const _Float16* __restrict__ wlds,
                  const float* __restrict__ b_f,
                  const float* __restrict__ b_b,
                  float* __restrict__ hf, float* __restrict__ hb)
{
    __shared__ h8_t  wsh8[8192];      // 128 KB weight tail
    __shared__ h8_t  hbuf8[32];       // 256 h values fp16
    __shared__ float gbuf[1024];

    const int dir = blockIdx.x >> 6;
    const int b   = blockIdx.x & 63;
    const int q   = threadIdx.x;

    const _Float16* __restrict__ gin = dir ? gin_b : gin_f;
    const float*    __restrict__ bs  = dir ? b_b : b_f;
    float*          __restrict__ hout = dir ? hb : hf;

    {   // stage LDS weight tail (identical image for all blocks of a dir)
        const h8_t* src = (const h8_t*)wlds + (size_t)dir * 8192 + q;
        #pragma unroll
        for (int j = 0; j < 16; ++j) wsh8[j * 512 + q] = src[(size_t)j * 512];
    }

    // register-resident weights: 12 x h32 SSA values = 192 VGPRs
    const h32_t* wr = (const h32_t*)wreg + (size_t)dir * 6144 + q;
    h32_t W0 = wr[0 * 512], W1 = wr[1 * 512], W2 = wr[2 * 512];
    h32_t W3 = wr[3 * 512], W4 = wr[4 * 512], W5 = wr[5 * 512];
    h32_t X0 = wr[6 * 512], X1 = wr[7 * 512], X2 = wr[8 * 512];
    h32_t X3 = wr[9 * 512], X4 = wr[10 * 512], X5 = wr[11 * 512];

    const float bias0 = bs[q];
    const float bias1 = bs[q + 512];

    if (q < 32) {
        h8_t z = (h8_t)(_Float16)0.f;
        hbuf8[q] = z;
    }
    float c = 0.f;
    __syncthreads();

    const long tstr = 64 * 1024;
    const long hstr = 64 * 256;
    const _Float16* gp = gin + (size_t)(dir ? 511 : 0) * tstr + (size_t)b * 1024 + q;
    float*          hp = hout + (size_t)(dir ? 511 : 0) * hstr + (size_t)b * 256 + q;
    const long gstep = dir ? -tstr : tstr;
    const long hstep = dir ? -hstr : hstr;

    const h8_t* HB  = hbuf8;
    const h8_t* WS8 = wsh8;

    _Float16 gc0 = gp[0], gc1 = gp[512];

    for (int s = 0; s < T_; ++s) {
        // prefetch next step's gin (safe overread into adjacent ws region)
        _Float16 gn0 = gp[gstep], gn1 = gp[gstep + 512];

        float a0 = bias0 + (float)gc0;
        float a1 = bias1 + (float)gc1;

        GRP(W0, X0, 0);  GRP(W1, X1, 4);  GRP(W2, X2, 8);
        GRP(W3, X3, 12); GRP(W4, X4, 16); GRP(W5, X5, 20);
        DLDS(0); DLDS(1); DLDS(2); DLDS(3);

        gbuf[q] = a0;
        gbuf[q + 512] = a1;
        __syncthreads();
        if (q < 256) {
            float gi = gbuf[q], gf = gbuf[q + 256], gg = gbuf[q + 512], go = gbuf[q + 768];
            float si = 1.f / (1.f + expf(-gi));
            float sf = 1.f / (1.f + expf(-gf));
            float so = 1.f / (1.f + expf(-go));
            c = sf * c + si * tanhf(gg);
            float h = so * tanhf(c);
            hp[0] = h;
            ((_Float16*)hbuf8)[q] = (_Float16)h;
        }
        gc0 = gn0; gc1 = gn1;
        gp += gstep;
        hp += hstep;
        __syncthreads();
    }
}

// ---------------------------------------------------------------------------
// Kernel C: feats[m, o] = concat(hf[m], hb[m]) . w_out[o, :] + b_out[o]
// ---------------------------------------------------------------------------
__global__ __launch_bounds__(256)
void feats_proj(const float* __restrict__ hf, const float* __restrict__ hb,
                const float* __restrict__ w_out, const float* __restrict__ b_out,
                float* __restrict__ feats)
{
    const int lane = threadIdx.x & 63;
    const int wv   = threadIdx.x >> 6;
    const int m    = blockIdx.x * 4 + wv;
    const int o    = lane & 15;
    const int qq   = lane >> 4;

    const float* hsrc = (qq < 2) ? (hf + (size_t)m * 256 + qq * 128)
                                 : (hb + (size_t)m * 256 + (qq - 2) * 128);
    const float4* h4 = (const float4*)hsrc;
    const float4* w4 = (const float4*)(w_out + o * 512 + qq * 128);

    float acc = 0.f;
    #pragma unroll
    for (int i = 0; i < 32; ++i) {
        float4 hv = h4[i], wvv = w4[i];
        acc = fmaf(hv.x, wvv.x, acc);
        acc = fmaf(hv.y, wvv.y, acc);
        acc = fmaf(hv.z, wvv.z, acc);
        acc = fmaf(hv.w, wvv.w, acc);
    }
    acc += __shfl_xor(acc, 16, 64);
    acc += __shfl_xor(acc, 32, 64);
    if (lane < 16) feats[(size_t)m * 16 + o] = acc + b_out[o];
}

// ---------------------------------------------------------------------------
// Kernel D: Viterbi + backtrace. One wave per batch element; feats loaded
// 4 steps at a time across the wave (lanes 0..63 = 4 rows x 16 tags).
// ---------------------------------------------------------------------------
__global__ __launch_bounds__(64)
void viterbi(const float* __restrict__ feats, const float* __restrict__ trans,
             float* __restrict__ out)
{
    __shared__ unsigned char bp[T_][16];
    const int b    = blockIdx.x;
    const int lane = threadIdx.x;
    const int l15  = lane & 15;

    float tr[16];
    #pragma unroll
    for (int p = 0; p < 16; ++p)
        tr[p] = (lane < 16) ? trans[lane * 16 + p] : 0.f;

    float fv = (lane == START_) ? 0.f : NEG_;

    for (int t4 = 0; t4 < T_; t4 += 4) {
        float fblk = feats[((size_t)(t4 + (lane >> 4)) * 64 + b) * 16 + l15];
        #pragma unroll
        for (int tt = 0; tt < 4; ++tt) {
            const int t = t4 + tt;
            float best = -3.4e38f; int arg = 0;
            #pragma unroll
            for (int p = 0; p < 16; ++p) {
                float s = __shfl(fv, p, 64) + tr[p];
                if (s > best) { best = s; arg = p; }
            }
            float ft = __shfl(fblk, tt * 16 + l15, 64);
            if (lane < 16) {
                fv = best + ft;
                bp[t][lane] = (unsigned char)arg;
            }
        }
    }

    float term = fv + ((lane < 16) ? trans[STOP_ * 16 + lane] : 0.f);
    float v  = (lane < 16) ? term : -3.4e38f;
    int  idx = (lane < 16) ? lane : (1 << 20);
    #pragma unroll
    for (int off = 1; off < 64; off <<= 1) {
        float v2 = __shfl_xor(v, off, 64);
        int   i2 = __shfl_xor(idx, off, 64);
        if (v2 > v || (v2 == v && i2 < idx)) { v = v2; idx = i2; }
    }
    __syncthreads();
    if (lane == 0) {
        out[b] = v;
        int tag = idx;
        for (int t = T_ - 1; t >= 0; --t) {
            out[64 + (size_t)t * 64 + b] = (float)tag;
            tag = bp[t][tag];
        }
    }
}

// ---------------------------------------------------------------------------
extern "C" void kernel_launch(void* const* d_in, const int* in_sizes, int n_in,
                              void* d_out, int out_size, void* d_ws, size_t ws_size,
                              hipStream_t stream) {
    const int*   sentence = (const int*)d_in[0];
    const float* emb      = (const float*)d_in[1];
    const float* w_ih_f   = (const float*)d_in[2];
    const float* w_hh_f   = (const float*)d_in[3];
    const float* b_f      = (const float*)d_in[4];
    const float* w_ih_b   = (const float*)d_in[5];
    const float* w_hh_b   = (const float*)d_in[6];
    const float* b_b      = (const float*)d_in[7];
    const float* w_out    = (const float*)d_in[8];
    const float* b_out    = (const float*)d_in[9];
    const float* trans    = (const float*)d_in[10];
    float* out = (float*)d_out;

    // workspace: gin_f|gin_b (fp16 64MB ea) | hf|hb (fp32 32MB ea) |
    //            feats (2MB) | wreg (768KB) | wlds (256KB) | wih16 (1MB)
    _Float16* gin_f = (_Float16*)d_ws;
    _Float16* gin_b = gin_f + (size_t)T_ * B_ * G_;
    float* hf    = (float*)(gin_b + (size_t)T_ * B_ * G_);
    float* hb    = hf + (size_t)T_ * B_ * H_;
    float* feats = hb + (size_t)T_ * B_ * H_;
    _Float16* wreg  = (_Float16*)(feats + (size_t)T_ * B_ * K_);
    _Float16* wlds  = wreg + 393216;
    _Float16* wih16 = wlds + 131072;

    prep_weights<<<368, 256, 0, stream>>>(w_hh_f, w_hh_b, w_ih_f, w_ih_b,
                                          wreg, wlds, wih16);
    gates_mfma<<<dim3(512, 2), 256, 0, stream>>>(sentence, emb, wih16,
                                                 gin_f, gin_b);
    lstm_persist<<<128, 512, 0, stream>>>(gin_f, gin_b, wreg, wlds,
                                          b_f, b_b, hf, hb);
    feats_proj<<<8192, 256, 0, stream>>>(hf, hb, w_out, b_out, feats);
    viterbi<<<64, 64, 0, stream>>>(feats, trans, out);
}